// Round 1
// baseline (968.312 us; speedup 1.0000x reference)
//
#include <hip/hip_runtime.h>
#include <math.h>

#define NPTS 8192
#define DIM 32
#define TILE 128
#define NT (NPTS / TILE)              // 64 tiles per side
#define NTP (NT * (NT + 1) / 2)       // 2080 upper-tri tile pairs
#define NBINS 4096
#define BIN_SCALE 20.0f               // bins per unit d^2 -> covers d^2 in [0, 204.8]
#define NR 16
#define MAXP 512

// ---------------- kernel 0: squared norms ----------------
__global__ void k_sq(const float* __restrict__ pts, float* __restrict__ sq) {
    int i = blockIdx.x * blockDim.x + threadIdx.x;
    if (i >= NPTS) return;
    const float4* r = (const float4*)(pts + (size_t)i * DIM);
    float s = 0.f;
#pragma unroll
    for (int q = 0; q < DIM / 4; ++q) {
        float4 v = r[q];
        s += v.x * v.x + v.y * v.y + v.z * v.z + v.w * v.w;
    }
    sq[i] = s;
}

// ---------------- kernel 1: pairwise d^2 histogram ----------------
// Persistent grid of P workgroups; each owns a private LDS histogram and
// flushes it to parts[blockIdx.x * NBINS] with plain stores at the end.
__global__ __launch_bounds__(256, 2)
void k_hist(const float4* __restrict__ p4, const float* __restrict__ sq,
            unsigned* __restrict__ parts) {
    __shared__ unsigned hist[NBINS];          // 16 KB
    __shared__ float4 At[8][TILE];            // 16 KB  (seg-major, swizzled cols)
    __shared__ float4 Bt[8][TILE];            // 16 KB
    const int tid = threadIdx.x;
    const int tx = tid & 15, ty = tid >> 4;   // 16x16 thread grid, 8x8 regs each
    for (int b = tid; b < NBINS; b += 256) hist[b] = 0u;
    const int P = gridDim.x;

    for (int tp = blockIdx.x; tp < NTP; tp += P) {
        // decode upper-triangular tile pair (ti <= tj)
        int ti = 0, rr = tp;
        while (rr >= NT - ti) { rr -= NT - ti; ++ti; }
        const int tj = ti + rr;

        __syncthreads();   // previous iteration's reads of At/Bt done
        // load tiles: idx enumerates 1024 float4s, global reads fully coalesced,
        // column swizzle sp = p ^ ((p>>3)&7) makes fragment reads conflict-free
#pragma unroll
        for (int q = 0; q < 4; ++q) {
            const int idx = tid + 256 * q;
            const int seg = idx & 7;          // which 4 coords (k = 4*seg..)
            const int p = idx >> 3;           // point within tile
            const int sp = p ^ ((p >> 3) & 7);
            At[seg][sp] = p4[(size_t)(ti * TILE + p) * 8 + seg];
            Bt[seg][sp] = p4[(size_t)(tj * TILE + p) * 8 + seg];
        }
        __syncthreads();

        float acc[8][8];
#pragma unroll
        for (int m = 0; m < 8; ++m)
#pragma unroll
            for (int n = 0; n < 8; ++n) acc[m][n] = 0.f;

#pragma unroll
        for (int seg = 0; seg < 8; ++seg) {
            float4 af[8];
#pragma unroll
            for (int m = 0; m < 8; ++m)
                af[m] = At[seg][ty * 8 + (m ^ (ty & 7))];
#pragma unroll
            for (int n = 0; n < 8; ++n) {
                const float4 bv = Bt[seg][tx * 8 + (n ^ (tx & 7))];
#pragma unroll
                for (int m = 0; m < 8; ++m) {
                    acc[m][n] = fmaf(af[m].x, bv.x, acc[m][n]);
                    acc[m][n] = fmaf(af[m].y, bv.y, acc[m][n]);
                    acc[m][n] = fmaf(af[m].z, bv.z, acc[m][n]);
                    acc[m][n] = fmaf(af[m].w, bv.w, acc[m][n]);
                }
            }
        }

        float sA[8], sB[8];
#pragma unroll
        for (int m = 0; m < 8; ++m) sA[m] = sq[ti * TILE + ty * 8 + m];
#pragma unroll
        for (int n = 0; n < 8; ++n) sB[n] = sq[tj * TILE + tx * 8 + n];

        const bool diag = (ti == tj);
#pragma unroll
        for (int m = 0; m < 8; ++m) {
#pragma unroll
            for (int n = 0; n < 8; ++n) {
                const float d2 = fmaf(-2.f, acc[m][n], sA[m] + sB[n]);
                const float bf_ = fminf(fmaxf(d2, 0.f) * BIN_SCALE, (float)(NBINS - 1));
                const int bin = (int)bf_;
                if (!diag || ((ty * 8 + m) < (tx * 8 + n)))
                    atomicAdd(&hist[bin], 1u);
            }
        }
    }

    __syncthreads();
    unsigned* my = parts + (size_t)blockIdx.x * NBINS;
    for (int b = tid; b < NBINS; b += 256) my[b] = hist[b];
}

// ---------------- kernel 2: reduce partials, sigmoid sums ----------------
__global__ void k_sums(const unsigned* __restrict__ parts, int P,
                       const float* __restrict__ rvals, double* __restrict__ sums) {
    const int b = blockIdx.x * 256 + threadIdx.x;
    unsigned long long c = 0;
    for (int p = 0; p < P; ++p) c += parts[(size_t)p * NBINS + b];

    double local[NR + 1];
#pragma unroll
    for (int t = 0; t < NR; ++t) local[t] = 0.0;
    local[NR] = (double)c;   // pair count

    if (c) {
        const double d = sqrt(((double)b + 0.5) / (double)BIN_SCALE);
#pragma unroll
        for (int t = 0; t < NR; ++t) {
            const double x = 10.0 * ((double)rvals[t] - d);
            double s;
            if (x >= 0.0) s = 1.0 / (1.0 + exp(-x));
            else          { const double e = exp(x); s = e / (1.0 + e); }
            local[t] = (double)c * s;
        }
    }

    // wave(64) reduction, then one atomic per wave per value
#pragma unroll
    for (int off = 32; off > 0; off >>= 1) {
#pragma unroll
        for (int t = 0; t <= NR; ++t)
            local[t] += __shfl_down(local[t], off);
    }
    if ((threadIdx.x & 63) == 0) {
#pragma unroll
        for (int t = 0; t <= NR; ++t) atomicAdd(&sums[t], local[t]);
    }
}

// ---------------- kernel 3: log-log regression ----------------
__global__ void k_fit(const double* __restrict__ sums, const float* __restrict__ rvals,
                      float* __restrict__ out) {
    const double cnt = sums[NR];
    double Sx = 0, Sy = 0, Sxx = 0, Sxy = 0;
#pragma unroll
    for (int t = 0; t < NR; ++t) {
        const double x = log((double)rvals[t]);
        const double y = log(sums[t] / cnt);
        Sx += x; Sy += y; Sxx += x * x; Sxy += x * y;
    }
    const double R = (double)NR;
    const double slope = (R * Sxy - Sx * Sy) / (R * Sxx - Sx * Sx);
    out[0] = (float)(-slope);
}

extern "C" void kernel_launch(void* const* d_in, const int* in_sizes, int n_in,
                              void* d_out, int out_size, void* d_ws, size_t ws_size,
                              hipStream_t stream) {
    const float* pts = (const float*)d_in[0];
    const float* rv  = (const float*)d_in[1];
    float* out = (float*)d_out;
    char* ws = (char*)d_ws;

    float* sq = (float*)ws;                        // 32 KB
    const size_t off_parts = 32768;
    size_t avail = (ws_size > off_parts + 1024) ? (ws_size - off_parts - 1024) : 0;
    int P = (int)(avail / ((size_t)NBINS * sizeof(unsigned)));
    if (P > MAXP) P = MAXP;
    if (P < 1) P = 1;
    unsigned* parts = (unsigned*)(ws + off_parts);
    double* sums = (double*)(ws + off_parts + (size_t)P * NBINS * sizeof(unsigned));

    hipMemsetAsync(sums, 0, (NR + 1) * sizeof(double), stream);
    k_sq<<<NPTS / 256, 256, 0, stream>>>(pts, sq);
    k_hist<<<P, 256, 0, stream>>>((const float4*)pts, sq, parts);
    k_sums<<<NBINS / 256, 256, 0, stream>>>(parts, P, rv, sums);
    k_fit<<<1, 1, 0, stream>>>(sums, rv, out);
}

// Round 2
// 560.488 us; speedup vs baseline: 1.7276x; 1.7276x over previous
//
#include <hip/hip_runtime.h>
#include <math.h>

#define NPTS 8192
#define DIM 32
#define TILE 128
#define NT (NPTS / TILE)              // 64 tiles per side
#define NTP (NT * (NT + 1) / 2)       // 2080 upper-tri tile pairs
#define NBINS 4096
#define BIN_SCALE 20.0f               // bins per unit d^2 -> covers d^2 in [0, 204.8]
#define NR 16
#define MAXP 512
#define TM 8
#define TN 4

// ---------------- kernel 0: squared norms ----------------
__global__ void k_sq(const float* __restrict__ pts, float* __restrict__ sq) {
    int i = blockIdx.x * blockDim.x + threadIdx.x;
    if (i >= NPTS) return;
    const float4* r = (const float4*)(pts + (size_t)i * DIM);
    float s = 0.f;
#pragma unroll
    for (int q = 0; q < DIM / 4; ++q) {
        float4 v = r[q];
        s += v.x * v.x + v.y * v.y + v.z * v.z + v.w * v.w;
    }
    sq[i] = s;
}

// ---------------- kernel 1: pairwise d^2 histogram ----------------
// 512 threads = 32x16 grid; each thread owns 8 rows x 4 strided cols.
// acc[8][4] = 32 VGPRs, bv[4] = 16 VGPRs -> ~80 VGPR peak, no spill.
__global__ __launch_bounds__(512, 2)
void k_hist(const float4* __restrict__ p4, const float* __restrict__ sq,
            unsigned* __restrict__ parts) {
    __shared__ unsigned hist[NBINS];          // 16 KB
    __shared__ float4 At[8][TILE];            // 16 KB  (seg-major, cols XOR seg)
    __shared__ float4 Bt[8][TILE];            // 16 KB
    const int tid = threadIdx.x;
    const int tx = tid & 31, ty = tid >> 5;
    for (int b = tid; b < NBINS; b += 512) hist[b] = 0u;
    const int P = gridDim.x;

    for (int tp = blockIdx.x; tp < NTP; tp += P) {
        // decode upper-triangular tile pair (ti <= tj)
        int ti = 0, rr = tp;
        while (rr >= NT - ti) { rr -= NT - ti; ++ti; }
        const int tj = ti + rr;

        __syncthreads();   // previous iteration's reads of At/Bt done
        // stage tiles: global reads perfectly contiguous (idx == p*8+seg),
        // LDS column swizzled by ^seg -> staging writes spread over bank quads
#pragma unroll
        for (int q = 0; q < 2; ++q) {
            const int idx = tid + 512 * q;    // 0..1023
            const int seg = idx & 7;          // which 4 coords
            const int p = idx >> 3;           // point within tile
            const int sp = p ^ seg;
            At[seg][sp] = p4[(size_t)ti * 1024 + idx];
            Bt[seg][sp] = p4[(size_t)tj * 1024 + idx];
        }
        __syncthreads();

        float acc[TM][TN];
#pragma unroll
        for (int m = 0; m < TM; ++m)
#pragma unroll
            for (int n = 0; n < TN; ++n) acc[m][n] = 0.f;

#pragma unroll
        for (int seg = 0; seg < 8; ++seg) {
            float4 bv[TN];
#pragma unroll
            for (int n = 0; n < TN; ++n)
                bv[n] = Bt[seg][(n * 32 + tx) ^ seg];   // contiguous, conflict-free
#pragma unroll
            for (int m = 0; m < TM; ++m) {
                const float4 a = At[seg][(ty * 8 + m) ^ seg];  // half-wave broadcast
#pragma unroll
                for (int n = 0; n < TN; ++n) {
                    acc[m][n] = fmaf(a.x, bv[n].x, acc[m][n]);
                    acc[m][n] = fmaf(a.y, bv[n].y, acc[m][n]);
                    acc[m][n] = fmaf(a.z, bv[n].z, acc[m][n]);
                    acc[m][n] = fmaf(a.w, bv[n].w, acc[m][n]);
                }
            }
        }

        float sA[TM], sB[TN];
#pragma unroll
        for (int m = 0; m < TM; ++m) sA[m] = sq[ti * TILE + ty * 8 + m];
#pragma unroll
        for (int n = 0; n < TN; ++n) sB[n] = sq[tj * TILE + n * 32 + tx];

        const bool diag = (ti == tj);
#pragma unroll
        for (int m = 0; m < TM; ++m) {
#pragma unroll
            for (int n = 0; n < TN; ++n) {
                const float d2 = fmaf(-2.f, acc[m][n], sA[m] + sB[n]);
                const float bf_ = fminf(fmaxf(d2, 0.f) * BIN_SCALE, (float)(NBINS - 1));
                const int bin = (int)bf_;
                if (!diag || ((ty * 8 + m) < (n * 32 + tx)))
                    atomicAdd(&hist[bin], 1u);
            }
        }
    }

    __syncthreads();
    unsigned* my = parts + (size_t)blockIdx.x * NBINS;
    for (int b = tid; b < NBINS; b += 512) my[b] = hist[b];
}

// ---------------- kernel 2: reduce partials, sigmoid sums ----------------
__global__ void k_sums(const unsigned* __restrict__ parts, int P,
                       const float* __restrict__ rvals, double* __restrict__ sums) {
    const int b = blockIdx.x * 256 + threadIdx.x;
    unsigned long long c;
    {
        unsigned c8[8];
#pragma unroll
        for (int u = 0; u < 8; ++u) c8[u] = 0u;
        int p = 0;
        for (; p + 8 <= P; p += 8) {          // 8 independent loads in flight
#pragma unroll
            for (int u = 0; u < 8; ++u)
                c8[u] += parts[(size_t)(p + u) * NBINS + b];
        }
        for (; p < P; ++p) c8[0] += parts[(size_t)p * NBINS + b];
        unsigned long long t = 0;
#pragma unroll
        for (int u = 0; u < 8; ++u) t += c8[u];
        c = t;
    }

    double local[NR + 1];
#pragma unroll
    for (int t = 0; t < NR; ++t) local[t] = 0.0;
    local[NR] = (double)c;   // pair count

    if (c) {
        const double d = sqrt(((double)b + 0.5) / (double)BIN_SCALE);
#pragma unroll
        for (int t = 0; t < NR; ++t) {
            const double x = 10.0 * ((double)rvals[t] - d);
            double s;
            if (x >= 0.0) s = 1.0 / (1.0 + exp(-x));
            else          { const double e = exp(x); s = e / (1.0 + e); }
            local[t] = (double)c * s;
        }
    }

    // wave(64) reduction, then one atomic per wave per value
#pragma unroll
    for (int off = 32; off > 0; off >>= 1) {
#pragma unroll
        for (int t = 0; t <= NR; ++t)
            local[t] += __shfl_down(local[t], off);
    }
    if ((threadIdx.x & 63) == 0) {
#pragma unroll
        for (int t = 0; t <= NR; ++t) atomicAdd(&sums[t], local[t]);
    }
}

// ---------------- kernel 3: log-log regression ----------------
__global__ void k_fit(const double* __restrict__ sums, const float* __restrict__ rvals,
                      float* __restrict__ out) {
    const double cnt = sums[NR];
    double Sx = 0, Sy = 0, Sxx = 0, Sxy = 0;
#pragma unroll
    for (int t = 0; t < NR; ++t) {
        const double x = log((double)rvals[t]);
        const double y = log(sums[t] / cnt);
        Sx += x; Sy += y; Sxx += x * x; Sxy += x * y;
    }
    const double R = (double)NR;
    const double slope = (R * Sxy - Sx * Sy) / (R * Sxx - Sx * Sx);
    out[0] = (float)(-slope);
}

extern "C" void kernel_launch(void* const* d_in, const int* in_sizes, int n_in,
                              void* d_out, int out_size, void* d_ws, size_t ws_size,
                              hipStream_t stream) {
    const float* pts = (const float*)d_in[0];
    const float* rv  = (const float*)d_in[1];
    float* out = (float*)d_out;
    char* ws = (char*)d_ws;

    float* sq = (float*)ws;                        // 32 KB
    const size_t off_parts = 32768;
    size_t avail = (ws_size > off_parts + 1024) ? (ws_size - off_parts - 1024) : 0;
    int P = (int)(avail / ((size_t)NBINS * sizeof(unsigned)));
    if (P > MAXP) P = MAXP;
    if (P < 1) P = 1;
    unsigned* parts = (unsigned*)(ws + off_parts);
    double* sums = (double*)(ws + off_parts + (size_t)P * NBINS * sizeof(unsigned));

    hipMemsetAsync(sums, 0, (NR + 1) * sizeof(double), stream);
    k_sq<<<NPTS / 256, 256, 0, stream>>>(pts, sq);
    k_hist<<<P, 512, 0, stream>>>((const float4*)pts, sq, parts);
    k_sums<<<NBINS / 256, 256, 0, stream>>>(parts, P, rv, sums);
    k_fit<<<1, 1, 0, stream>>>(sums, rv, out);
}